// Round 17
// baseline (289.149 us; speedup 1.0000x reference)
//
#include <hip/hip_runtime.h>

// SSIM fused kernel, round 12 RESUBMIT x6 (R11-R16 benches failed: GPUAcquisitionTimeout).
// BARRIER-FREE wave-local stage handoff.
// B=16, C=3, H=W=768, 11-tap separable Gaussian, VALID -> 758x758; out = per-batch mean [16].
//
// Model (R5-R11): 278 VALU inst/thread/step x 2cyc x 3 waves = 1668 busy-cyc vs
// measured 2453-cyc step => VALUBusy 68.0% (matches rocprof exactly). 785 idle
// cyc/SIMD/step where NO wave issues. Scheduling tweaks all null; occupancy capped
// (ring=64 VGPR). Remaining suspect: barrier straggler waits (block's 4 waves on 4
// SIMDs, cross-block interference desyncs them; 15 rendezvous/block).
//
// THE CHANGE: remap stage A so wave w produces all 4 rows for cols [64w,64w+64)
// (sA = t&3, cg = t>>2) — exactly the cols wave w's stage B consumes. The A->B
// handoff becomes intra-wave: LDS ds ops of one wave execute in order, so
// s_waitcnt lgkmcnt(0) alone (NO s_barrier) gives cross-lane visibility.
//  - ALL 15 barriers deleted. Waves free-run; stragglers can't couple.
//  - Ping-pong dropped (same-wave W(m+1)-after-R(m) is pipe-ordered): 33->16.6 KB.
//  - LDS [field][row][stride 260]: b128 writes 16B-aligned; b32 reads stride-1.
//  - Per-(row,col) arithmetic IDENTICAL (thread-assignment permutation only)
//    => absmax 0.0 expected. A race from a wrong ordering assumption would blow
//    up absmax loudly.
// Keep: (3,3) pin, R6 prefetch (reg-set rotation via p&1), packed f32x2 chains,
// field-major b32 reads, stage-B warm-up skip (m<2), p-unroll(4) for STATIC ring
// indexing (rule #20: ring must never be runtime-indexed — R10's real failure).

typedef float f32x2 __attribute__((ext_vector_type(2)));

#define H_IMG 768
#define W_IMG 768
#define OH 758
#define OW_TOT 758
#define OWS 256   // output cols per strip
#define NSEG 16   // vertical segments
#define LSTR 260  // LDS col stride: mult of 4 (b128 align), 260%32=4 row bank-shift

// Wave-local handoff: drain LDS writes (in-order DS pipe, same wave) — no s_barrier.
#define WAIT_LDS() asm volatile("s_waitcnt lgkmcnt(0)" ::: "memory")
// Compiler-only memory fence (keeps next step's ds_writes from hoisting above reads).
#define FENCE_C()  asm volatile("" ::: "memory")

static __device__ __forceinline__ f32x2 mk2(float a, float b) {
    f32x2 r; r.x = a; r.y = b; return r;
}

struct RowRegs {
    float4 xa, xb, xc, ya, yb, yc;
    float2 xd, yd;
};

static __device__ __forceinline__ void load_rows(RowRegs& rr,
        const float* __restrict__ xr, const float* __restrict__ yr,
        int k0, int k1, int k2, int k3) {
    rr.xa = *(const float4*)(xr + k0);
    rr.xb = *(const float4*)(xr + k1);
    rr.xc = *(const float4*)(xr + k2);
    rr.xd = *(const float2*)(xr + k3);
    rr.ya = *(const float4*)(yr + k0);
    rr.yb = *(const float4*)(yr + k1);
    rr.yc = *(const float4*)(yr + k2);
    rr.yd = *(const float2*)(yr + k3);
}

__global__ void ssim_zero_out(float* __restrict__ out) {
    if (threadIdx.x < 16) out[threadIdx.x] = 0.0f;
}

__attribute__((amdgpu_flat_work_group_size(256, 256), amdgpu_waves_per_eu(3, 3)))
__global__ void ssim_fused(const float* __restrict__ X, const float* __restrict__ Y,
                           const float* __restrict__ Wg, float* __restrict__ out) {
    const float C1 = 1e-4f, C2 = 9e-4f, EPS = 1e-8f;
    const float INV_COUNT = 1.0f / (3.0f * 758.0f * 758.0f);

    const int t = threadIdx.x;
    int bx = blockIdx.x;
    const int seg = bx & (NSEG - 1); bx >>= 4;
    const int strip = bx % 3; bx /= 3;
    const int ch = bx % 3;
    const int b  = bx / 3;

    const int R0 = (OH * seg) / NSEG;
    const int Rend = (OH * (seg + 1)) / NSEG;
    const int hseg = Rend - R0;
    const int c0 = strip * OWS;

    const float* Xi = X + (size_t)(b * 3 + ch) * (H_IMG * W_IMG);
    const float* Yi = Y + (size_t)(b * 3 + ch) * (H_IMG * W_IMG);

    // Broadcast weights as packed pairs (pk_fma src).
    f32x2 ww[11];
#pragma unroll
    for (int k = 0; k < 11; ++k) { float wk = Wg[k]; ww[k] = mk2(wk, wk); }

    // Single-buffer LDS handoff, wave-local: [field: mux,muy,sumsq,prod][row][col]
    __shared__ float hb[4][4][LSTR];   // 16.6 KB
    __shared__ float red[4];

    // Stage A mapping (WAVE-LOCAL): lane quad = 4 rows, quads walk cols.
    // Wave w (t in [64w,64w+64)) produces rows 0..3 for cols [64w,64w+64) —
    // exactly the cols wave w's stage B (thread t -> col c0+t) consumes.
    const int sA = t & 3;
    const int cg = t >> 2;
    const int colbase = c0 + 4 * cg;
    const int k0 = min(colbase,      W_IMG - 4);
    const int k1 = min(colbase + 4,  W_IMG - 4);
    const int k2 = min(colbase + 8,  W_IMG - 4);
    const int k3 = min(colbase + 12, W_IMG - 2);

    // Stage B: packed ring-16. rg01 = (mu_x, mu_y), rg23 = (x2+y2, xy). Slot of rel row r = r & 15.
    f32x2 rg01[16], rg23[16];
#pragma unroll
    for (int j = 0; j < 16; ++j) { rg01[j] = mk2(0.f, 0.f); rg23[j] = mk2(0.f, 0.f); }

    const bool colok = (c0 + t) < OW_TOT;
    float local = 0.0f;
    const int M = (hseg + 13) >> 2;   // macro-iters of 4 input rows

    // Prologue: load row-group m=0 into r0.
    RowRegs r0, r1;
    {
        int rr = min(R0 + sA, H_IMG - 1);
        load_rows(r0, Xi + (size_t)rr * W_IMG, Yi + (size_t)rr * W_IMG, k0, k1, k2, k3);
    }

    for (int mb = 0; mb < M; mb += 4) {
#pragma unroll
        for (int p = 0; p < 4; ++p) {
            const int m = mb + p;
            if (m < M) {
                const int pr = p & 1;             // prefetch register-set parity
                RowRegs& cur = pr ? r1 : r0;
                RowRegs& nxt = pr ? r0 : r1;

                // ---- Prefetch row-group m+1 (issue-early; consumed next step) ----
                if (m + 1 < M) {
                    int rn = R0 + 4 * (m + 1) + sA;
                    rn = min(rn, H_IMG - 1);
                    load_rows(nxt, Xi + (size_t)rn * W_IMG, Yi + (size_t)rn * W_IMG,
                              k0, k1, k2, k3);
                }

                // ---------------- Stage A: horizontal blur (packed, pass-split) ----------------
                {
                    f32x2 v[14] = {
                        mk2(cur.xa.x, cur.ya.x), mk2(cur.xa.y, cur.ya.y),
                        mk2(cur.xa.z, cur.ya.z), mk2(cur.xa.w, cur.ya.w),
                        mk2(cur.xb.x, cur.yb.x), mk2(cur.xb.y, cur.yb.y),
                        mk2(cur.xb.z, cur.yb.z), mk2(cur.xb.w, cur.yb.w),
                        mk2(cur.xc.x, cur.yc.x), mk2(cur.xc.y, cur.yc.y),
                        mk2(cur.xc.z, cur.yc.z), mk2(cur.xc.w, cur.yc.w),
                        mk2(cur.xd.x, cur.yd.x), mk2(cur.xd.y, cur.yd.y)};

                    // Pass 1: mu chain -> LDS fields 0,1.
                    {
                        f32x2 hm[4];
#pragma unroll
                        for (int cc = 0; cc < 4; ++cc) {
                            f32x2 a = mk2(0.f, 0.f);
#pragma unroll
                            for (int k = 0; k < 11; ++k)
                                a = __builtin_elementwise_fma(ww[k], v[cc + k], a);
                            hm[cc] = a;
                        }
                        *(float4*)&hb[0][sA][4 * cg] = make_float4(hm[0].x, hm[1].x, hm[2].x, hm[3].x);
                        *(float4*)&hb[1][sA][4 * cg] = make_float4(hm[0].y, hm[1].y, hm[2].y, hm[3].y);
                    }
                    // Square in place: v <- (x^2+y^2, x*y).
#pragma unroll
                    for (int j = 0; j < 14; ++j) {
                        const float xx = v[j].x, yy = v[j].y;
                        v[j] = mk2(fmaf(xx, xx, yy * yy), xx * yy);
                    }
                    // Pass 2: (sumsq, prod) chain -> LDS fields 2,3.
                    {
                        f32x2 hs[4];
#pragma unroll
                        for (int cc = 0; cc < 4; ++cc) {
                            f32x2 a = mk2(0.f, 0.f);
#pragma unroll
                            for (int k = 0; k < 11; ++k)
                                a = __builtin_elementwise_fma(ww[k], v[cc + k], a);
                            hs[cc] = a;
                        }
                        *(float4*)&hb[2][sA][4 * cg] = make_float4(hs[0].x, hs[1].x, hs[2].x, hs[3].x);
                        *(float4*)&hb[3][sA][4 * cg] = make_float4(hs[0].y, hs[1].y, hs[2].y, hs[3].y);
                    }
                }
                // Wave-local handoff: in-order DS pipe + lgkmcnt(0). NO s_barrier.
                WAIT_LDS();

                // ---------------- Stage B: insert + vertical blur (packed) + SSIM ----------------
                {
                    // b32 stride-1 reads assembled straight into pair halves.
#pragma unroll
                    for (int s2 = 0; s2 < 4; ++s2) {
                        const int sl = (4 * p + s2) & 15;
                        rg01[sl] = mk2(hb[0][s2][t], hb[1][s2][t]);
                        rg23[sl] = mk2(hb[2][s2][t], hb[3][s2][t]);
                    }
                    // Steps m<2 only produce orel in [-10,-3]: all discarded (ring
                    // warm-up). Skip the vertical blur + SSIM entirely (uniform branch).
                    if (m >= 2) {
#pragma unroll
                        for (int s2 = 0; s2 < 4; ++s2) {
                            const int orel = 4 * m - 10 + s2;
                            f32x2 a01 = mk2(0.f, 0.f), a23 = mk2(0.f, 0.f);
#pragma unroll
                            for (int k = 0; k < 11; ++k) {
                                const int sl = (4 * p + s2 + k + 6) & 15;
                                a01 = __builtin_elementwise_fma(ww[k], rg01[sl], a01);
                                a23 = __builtin_elementwise_fma(ww[k], rg23[sl], a23);
                            }
                            const float a0 = a01.x, a1 = a01.y, a2 = a23.x, a3 = a23.y;
                            const float mux2 = a0 * a0;
                            const float muy2 = a1 * a1;
                            const float mxy  = a0 * a1;
                            const float sigsum = a2 - mux2 - muy2;  // sigma_x + sigma_y
                            const float sxy    = a3 - mxy;
                            const float num = (2.0f * mxy + C1) * (2.0f * sxy + C2);
                            const float den = (mux2 + muy2 + C1 + EPS) * (sigsum + C2 + EPS);
                            const float v = fmaxf(__fdividef(num, den), 0.0f);
                            if (colok && (orel >= 0) && (orel < hseg)) local += v;
                        }
                    }
                }
                // Keep next step's ds_writes (may-alias) from hoisting above these reads.
                FENCE_C();
            }
        }
    }

    // ---------------- block reduction + atomic (cross-wave: full barrier kept) ----------------
    float v = local;
#pragma unroll
    for (int off = 32; off > 0; off >>= 1) v += __shfl_down(v, off, 64);
    if ((t & 63) == 0) red[t >> 6] = v;
    __syncthreads();
    if (t == 0) {
        atomicAdd(&out[b], (red[0] + red[1] + red[2] + red[3]) * INV_COUNT);
    }
}

extern "C" void kernel_launch(void* const* d_in, const int* in_sizes, int n_in,
                              void* d_out, int out_size, void* d_ws, size_t ws_size,
                              hipStream_t stream) {
    const float* X  = (const float*)d_in[0];
    const float* Y  = (const float*)d_in[1];
    const float* Wg = (const float*)d_in[2];
    float* out = (float*)d_out;

    hipLaunchKernelGGL(ssim_zero_out, dim3(1), dim3(64), 0, stream, out);
    hipLaunchKernelGGL(ssim_fused, dim3(16 * 3 * 3 * NSEG), dim3(256), 0, stream,
                       X, Y, Wg, out);
}

// Round 18
// 269.381 us; speedup vs baseline: 1.0734x; 1.0734x over previous
//
#include <hip/hip_runtime.h>

// SSIM fused kernel, round 13: barrier-free (R12) + CONTIGUOUS quarter-wave LDS writes.
// B=16, C=3, H=W=768, 11-tap separable Gaussian, VALID -> 758x758; out = per-batch mean [16].
//
// R12 post-mortem (147 us, absmax 0.0, conflicts 0 -> 4.42M, VALUBusy 58%):
//   Correctness of the wave-local barrier-free handoff PROVEN. Perf regression traced
//   to the lane map: sA=t&3 put adjacent lanes on different rows (stride 260 dwords),
//   bank = 4*(sA+cg) mod 32 => 8 lanes per 4-bank group => 8-way conflict on every
//   ds_write_b128, serializing the DS pipe right before the lgkmcnt(0) wait.
//
// FIX (2 lines): sA = (t>>4)&3, cg = (t&15) | ((t>>6)<<4).
//   Wave w still covers rows 0..3 x cols [64w,64w+64) (wave-local preserved; cg is
//   the same bijection on 0..63), but each 16-lane quarter-wave now writes ONE row's
//   64 contiguous dwords -- consecutive lanes, b128: every 8-lane sub-group covers
//   exactly one full 32-bank rotation = conflict-free (R8's measured-0 pattern).
//
// This isolates the barrier-free effect: conflicts ~0 expected, then
//   dur ~100-115 us => straggler theory confirmed; dur ~128-133 us => neutral,
//   structural floor reached.
//
// Keep: (3,3) pin, prefetch (p&1 reg rotation), packed f32x2 chains, single-buffer
// LDS [field][row][260], stage-B warm-up skip (m<2), static ring indexing.

typedef float f32x2 __attribute__((ext_vector_type(2)));

#define H_IMG 768
#define W_IMG 768
#define OH 758
#define OW_TOT 758
#define OWS 256   // output cols per strip
#define NSEG 16   // vertical segments
#define LSTR 260  // LDS col stride (dwords): mult of 4 for b128 alignment

// Wave-local handoff: drain LDS writes (in-order DS pipe, same wave) — no s_barrier.
#define WAIT_LDS() asm volatile("s_waitcnt lgkmcnt(0)" ::: "memory")
// Compiler-only memory fence (keeps next step's ds_writes from hoisting above reads).
#define FENCE_C()  asm volatile("" ::: "memory")

static __device__ __forceinline__ f32x2 mk2(float a, float b) {
    f32x2 r; r.x = a; r.y = b; return r;
}

struct RowRegs {
    float4 xa, xb, xc, ya, yb, yc;
    float2 xd, yd;
};

static __device__ __forceinline__ void load_rows(RowRegs& rr,
        const float* __restrict__ xr, const float* __restrict__ yr,
        int k0, int k1, int k2, int k3) {
    rr.xa = *(const float4*)(xr + k0);
    rr.xb = *(const float4*)(xr + k1);
    rr.xc = *(const float4*)(xr + k2);
    rr.xd = *(const float2*)(xr + k3);
    rr.ya = *(const float4*)(yr + k0);
    rr.yb = *(const float4*)(yr + k1);
    rr.yc = *(const float4*)(yr + k2);
    rr.yd = *(const float2*)(yr + k3);
}

__global__ void ssim_zero_out(float* __restrict__ out) {
    if (threadIdx.x < 16) out[threadIdx.x] = 0.0f;
}

__attribute__((amdgpu_flat_work_group_size(256, 256), amdgpu_waves_per_eu(3, 3)))
__global__ void ssim_fused(const float* __restrict__ X, const float* __restrict__ Y,
                           const float* __restrict__ Wg, float* __restrict__ out) {
    const float C1 = 1e-4f, C2 = 9e-4f, EPS = 1e-8f;
    const float INV_COUNT = 1.0f / (3.0f * 758.0f * 758.0f);

    const int t = threadIdx.x;
    int bx = blockIdx.x;
    const int seg = bx & (NSEG - 1); bx >>= 4;
    const int strip = bx % 3; bx /= 3;
    const int ch = bx % 3;
    const int b  = bx / 3;

    const int R0 = (OH * seg) / NSEG;
    const int Rend = (OH * (seg + 1)) / NSEG;
    const int hseg = Rend - R0;
    const int c0 = strip * OWS;

    const float* Xi = X + (size_t)(b * 3 + ch) * (H_IMG * W_IMG);
    const float* Yi = Y + (size_t)(b * 3 + ch) * (H_IMG * W_IMG);

    // Broadcast weights as packed pairs (pk_fma src).
    f32x2 ww[11];
#pragma unroll
    for (int k = 0; k < 11; ++k) { float wk = Wg[k]; ww[k] = mk2(wk, wk); }

    // Single-buffer LDS handoff, wave-local: [field: mux,muy,sumsq,prod][row][col]
    __shared__ float hb[4][4][LSTR];   // 16.6 KB
    __shared__ float red[4];

    // Stage A mapping (WAVE-LOCAL + CONTIGUOUS WRITES):
    //   sA = quarter-wave id (16 lanes per row), cg = (t&15) within-quarter walk +
    //   16*(wave id). Wave w covers rows 0..3 x cols [64w,64w+64) (same as R12);
    //   each quarter-wave writes 64 contiguous dwords => conflict-free b128.
    const int sA = (t >> 4) & 3;
    const int cg = (t & 15) | ((t >> 6) << 4);
    const int colbase = c0 + 4 * cg;
    const int k0 = min(colbase,      W_IMG - 4);
    const int k1 = min(colbase + 4,  W_IMG - 4);
    const int k2 = min(colbase + 8,  W_IMG - 4);
    const int k3 = min(colbase + 12, W_IMG - 2);

    // Stage B: packed ring-16. rg01 = (mu_x, mu_y), rg23 = (x2+y2, xy). Slot of rel row r = r & 15.
    f32x2 rg01[16], rg23[16];
#pragma unroll
    for (int j = 0; j < 16; ++j) { rg01[j] = mk2(0.f, 0.f); rg23[j] = mk2(0.f, 0.f); }

    const bool colok = (c0 + t) < OW_TOT;
    float local = 0.0f;
    const int M = (hseg + 13) >> 2;   // macro-iters of 4 input rows

    // Prologue: load row-group m=0 into r0.
    RowRegs r0, r1;
    {
        int rr = min(R0 + sA, H_IMG - 1);
        load_rows(r0, Xi + (size_t)rr * W_IMG, Yi + (size_t)rr * W_IMG, k0, k1, k2, k3);
    }

    for (int mb = 0; mb < M; mb += 4) {
#pragma unroll
        for (int p = 0; p < 4; ++p) {
            const int m = mb + p;
            if (m < M) {
                const int pr = p & 1;             // prefetch register-set parity
                RowRegs& cur = pr ? r1 : r0;
                RowRegs& nxt = pr ? r0 : r1;

                // ---- Prefetch row-group m+1 (issue-early; consumed next step) ----
                if (m + 1 < M) {
                    int rn = R0 + 4 * (m + 1) + sA;
                    rn = min(rn, H_IMG - 1);
                    load_rows(nxt, Xi + (size_t)rn * W_IMG, Yi + (size_t)rn * W_IMG,
                              k0, k1, k2, k3);
                }

                // ---------------- Stage A: horizontal blur (packed, pass-split) ----------------
                {
                    f32x2 v[14] = {
                        mk2(cur.xa.x, cur.ya.x), mk2(cur.xa.y, cur.ya.y),
                        mk2(cur.xa.z, cur.ya.z), mk2(cur.xa.w, cur.ya.w),
                        mk2(cur.xb.x, cur.yb.x), mk2(cur.xb.y, cur.yb.y),
                        mk2(cur.xb.z, cur.yb.z), mk2(cur.xb.w, cur.yb.w),
                        mk2(cur.xc.x, cur.yc.x), mk2(cur.xc.y, cur.yc.y),
                        mk2(cur.xc.z, cur.yc.z), mk2(cur.xc.w, cur.yc.w),
                        mk2(cur.xd.x, cur.yd.x), mk2(cur.xd.y, cur.yd.y)};

                    // Pass 1: mu chain -> LDS fields 0,1.
                    {
                        f32x2 hm[4];
#pragma unroll
                        for (int cc = 0; cc < 4; ++cc) {
                            f32x2 a = mk2(0.f, 0.f);
#pragma unroll
                            for (int k = 0; k < 11; ++k)
                                a = __builtin_elementwise_fma(ww[k], v[cc + k], a);
                            hm[cc] = a;
                        }
                        *(float4*)&hb[0][sA][4 * cg] = make_float4(hm[0].x, hm[1].x, hm[2].x, hm[3].x);
                        *(float4*)&hb[1][sA][4 * cg] = make_float4(hm[0].y, hm[1].y, hm[2].y, hm[3].y);
                    }
                    // Square in place: v <- (x^2+y^2, x*y).
#pragma unroll
                    for (int j = 0; j < 14; ++j) {
                        const float xx = v[j].x, yy = v[j].y;
                        v[j] = mk2(fmaf(xx, xx, yy * yy), xx * yy);
                    }
                    // Pass 2: (sumsq, prod) chain -> LDS fields 2,3.
                    {
                        f32x2 hs[4];
#pragma unroll
                        for (int cc = 0; cc < 4; ++cc) {
                            f32x2 a = mk2(0.f, 0.f);
#pragma unroll
                            for (int k = 0; k < 11; ++k)
                                a = __builtin_elementwise_fma(ww[k], v[cc + k], a);
                            hs[cc] = a;
                        }
                        *(float4*)&hb[2][sA][4 * cg] = make_float4(hs[0].x, hs[1].x, hs[2].x, hs[3].x);
                        *(float4*)&hb[3][sA][4 * cg] = make_float4(hs[0].y, hs[1].y, hs[2].y, hs[3].y);
                    }
                }
                // Wave-local handoff: in-order DS pipe + lgkmcnt(0). NO s_barrier.
                WAIT_LDS();

                // ---------------- Stage B: insert + vertical blur (packed) + SSIM ----------------
                {
                    // b32 stride-1 reads assembled straight into pair halves.
#pragma unroll
                    for (int s2 = 0; s2 < 4; ++s2) {
                        const int sl = (4 * p + s2) & 15;
                        rg01[sl] = mk2(hb[0][s2][t], hb[1][s2][t]);
                        rg23[sl] = mk2(hb[2][s2][t], hb[3][s2][t]);
                    }
                    // Steps m<2 only produce orel in [-10,-3]: all discarded (ring
                    // warm-up). Skip the vertical blur + SSIM entirely (uniform branch).
                    if (m >= 2) {
#pragma unroll
                        for (int s2 = 0; s2 < 4; ++s2) {
                            const int orel = 4 * m - 10 + s2;
                            f32x2 a01 = mk2(0.f, 0.f), a23 = mk2(0.f, 0.f);
#pragma unroll
                            for (int k = 0; k < 11; ++k) {
                                const int sl = (4 * p + s2 + k + 6) & 15;
                                a01 = __builtin_elementwise_fma(ww[k], rg01[sl], a01);
                                a23 = __builtin_elementwise_fma(ww[k], rg23[sl], a23);
                            }
                            const float a0 = a01.x, a1 = a01.y, a2 = a23.x, a3 = a23.y;
                            const float mux2 = a0 * a0;
                            const float muy2 = a1 * a1;
                            const float mxy  = a0 * a1;
                            const float sigsum = a2 - mux2 - muy2;  // sigma_x + sigma_y
                            const float sxy    = a3 - mxy;
                            const float num = (2.0f * mxy + C1) * (2.0f * sxy + C2);
                            const float den = (mux2 + muy2 + C1 + EPS) * (sigsum + C2 + EPS);
                            const float v = fmaxf(__fdividef(num, den), 0.0f);
                            if (colok && (orel >= 0) && (orel < hseg)) local += v;
                        }
                    }
                }
                // Keep next step's ds_writes (may-alias) from hoisting above these reads.
                FENCE_C();
            }
        }
    }

    // ---------------- block reduction + atomic (cross-wave: full barrier kept) ----------------
    float v = local;
#pragma unroll
    for (int off = 32; off > 0; off >>= 1) v += __shfl_down(v, off, 64);
    if ((t & 63) == 0) red[t >> 6] = v;
    __syncthreads();
    if (t == 0) {
        atomicAdd(&out[b], (red[0] + red[1] + red[2] + red[3]) * INV_COUNT);
    }
}

extern "C" void kernel_launch(void* const* d_in, const int* in_sizes, int n_in,
                              void* d_out, int out_size, void* d_ws, size_t ws_size,
                              hipStream_t stream) {
    const float* X  = (const float*)d_in[0];
    const float* Y  = (const float*)d_in[1];
    const float* Wg = (const float*)d_in[2];
    float* out = (float*)d_out;

    hipLaunchKernelGGL(ssim_zero_out, dim3(1), dim3(64), 0, stream, out);
    hipLaunchKernelGGL(ssim_fused, dim3(16 * 3 * 3 * NSEG), dim3(256), 0, stream,
                       X, Y, Wg, out);
}